// Round 11
// baseline (559.928 us; speedup 1.0000x reference)
//
#include <hip/hip_runtime.h>
#include <hip/hip_bf16.h>
#include <cstdint>

#define S 8
#define NTOT 20000
#define NSUB 4000
#define NSUBP 4096   // padded K (32 x 128); Pt pad cols are zero
#define F 128
#define HID 64
#define NH 8
#define DH 8

typedef __attribute__((ext_vector_type(8))) short bf16x8;
typedef __attribute__((ext_vector_type(4))) short bf16x4;
typedef __attribute__((ext_vector_type(4))) float f32x4;

__device__ __forceinline__ short f2bf(float f) {
  union { __hip_bfloat16 h; short s; } u;
  u.h = __float2bfloat16(f);
  return u.s;
}

__device__ __forceinline__ void gload16(const void* gsrc, void* ldst) {
  __builtin_amdgcn_global_load_lds(
      (const __attribute__((address_space(1))) void*)gsrc,
      (__attribute__((address_space(3))) void*)ldst, 16, 0, 0);
}

// ---------------- position map
__global__ void k_pos_init(int* __restrict__ posIdx) {
  int t = blockIdx.x * 256 + threadIdx.x;
  if (t < NTOT * S) posIdx[t] = -1;
}

__global__ void k_pos_scatter(const int* __restrict__ nodes, int* __restrict__ posIdx) {
  int t = blockIdx.x * 256 + threadIdx.x;
  if (t < S * NSUB) {
    int s = t / NSUB, i = t - s * NSUB;
    posIdx[nodes[t] * S + s] = i;
  }
}

// ---------------- zero the K-pad columns of Pt (cols 4000..4095 for all s,j)
// 8*64 rows x 96 cols = 6144 bf16x8 stores
__global__ void k_pt_pad(short* __restrict__ Pt) {
  int t = blockIdx.x * 256 + threadIdx.x;      // 0..6143
  int row = t / 12, off = (t - row * 12) * 8;
  bf16x8 z = (bf16x8){0,0,0,0,0,0,0,0};
  *(bf16x8*)(Pt + (size_t)row * NSUBP + NSUB + off) = z;
}

// ---------------- Pt1 = (emb[nodes] @ W1)^T bf16 (stride NSUBP)
__global__ __launch_bounds__(256) void k_feat_w1(const int* __restrict__ nodes,
                                                 const float* __restrict__ emb,
                                                 const float* __restrict__ W1,
                                                 short* __restrict__ Pt) {
  __shared__ __align__(16) float feat[16][F];
  __shared__ float tr[64][17];
  int t = threadIdx.x;
  int s = blockIdx.x / 250;
  int i0 = (blockIdx.x - s * 250) * 16;
  int gr0 = blockIdx.x * 16;
  int lr = t >> 4, lc = (t & 15) * 8;
  int n = nodes[gr0 + lr];
  *(f32x4*)&feat[lr][lc]     = *(const f32x4*)(emb + (size_t)n * F + lc);
  *(f32x4*)&feat[lr][lc + 4] = *(const f32x4*)(emb + (size_t)n * F + lc + 4);
  __syncthreads();
  int j = t & 63, ig = t >> 6;
  float acc[4] = {0.f, 0.f, 0.f, 0.f};
  for (int k = 0; k < F; ++k) {
    float w = W1[k * HID + j];
    #pragma unroll
    for (int i = 0; i < 4; ++i) acc[i] += feat[ig * 4 + i][k] * w;
  }
  #pragma unroll
  for (int i = 0; i < 4; ++i) tr[j][ig * 4 + i] = acc[i];
  __syncthreads();
  int jr = t >> 2, seg = (t & 3) * 4;
  bf16x4 o;
  #pragma unroll
  for (int u = 0; u < 4; ++u) o[u] = f2bf(tr[jr][seg + u]);
  *(bf16x4*)(Pt + ((size_t)s * HID + jr) * NSUBP + i0 + seg) = o;
}

// ---------------- adj GEMM: BM=16, BK=128 (512B bursts/row), LDS-staged, dbuf
// grid 2000: s=bid&7 (XCD), mb=bid>>3 (0..249). block 256 = 4 waves.
// wave w computes rows m0..m0+15 x cols w*16..w*16+15 (single f32x4 acc).
// MODE 0: raw partial -> out. MODE 1: relu(acc+bias) -> out (H).
template<int MODE>
__global__ __launch_bounds__(256) void k_adj(const float* __restrict__ adj,
                                             const short* __restrict__ Pt,
                                             const float* __restrict__ bias,
                                             float* __restrict__ out) {
  __shared__ __align__(16) float As[2][16 * 128];   // 8KB/buf, chunk^(row&7)
  __shared__ __align__(16) short Bs[2][64 * 128];   // 16KB/buf, chunk^(col&7)
  int bid = blockIdx.x;
  int s = bid & 7, mb = bid >> 3;
  int m0 = mb * 16;
  int tid = threadIdx.x;
  int w = tid >> 6, lane = tid & 63, l15 = lane & 15, g = lane >> 4;
  const float* adjS = adj + (size_t)s * NSUB * NSUB;
  const short* PtS  = Pt  + (size_t)s * HID * (size_t)NSUBP;

  // ---- A staging: 2 wave-calls; call q covers rows w*4+q*2 + (lane>>5)
  const float* asrc[2];
  int aok[2], adst[2];
  #pragma unroll
  for (int q = 0; q < 2; ++q) {
    int r = w * 4 + q * 2 + (lane >> 5);           // 0..15
    int c = (lane & 31) ^ (r & 7);                 // logical 16B chunk (0..31)
    asrc[q] = adjS + (size_t)(m0 + r) * NSUB + c * 4;
    aok[q] = c * 4;
    adst[q] = (w * 2 + q) * 1024;
  }
  // ---- B staging: 4 wave-calls; call q covers cols w*16 + q*4 + (lane>>4)
  const short* bsrc[4];
  int bdst[4];
  #pragma unroll
  for (int q = 0; q < 4; ++q) {
    int col = w * 16 + q * 4 + (lane >> 4);        // 0..63
    int d = (lane & 15) ^ (col & 7);               // logical 16B chunk (0..15)
    bsrc[q] = PtS + (size_t)col * NSUBP + d * 8;
    bdst[q] = (w * 4 + q) * 1024;
  }

  char* A0 = (char*)&As[0][0];
  char* B0 = (char*)&Bs[0][0];

  // ---- fragment-read byte offsets (4 k-slices of 32)
  int aoff[4], boff[4];
  int cl = w * 16 + l15;
  #pragma unroll
  for (int kk = 0; kk < 4; ++kk) {
    int c0 = kk * 8 + g * 2;
    aoff[kk] = l15 * 512 + ((c0 ^ (l15 & 7)) * 16);
    boff[kk] = cl * 256 + (((kk * 4 + g) ^ (cl & 7)) * 16);
  }

  f32x4 acc = (f32x4){0.f, 0.f, 0.f, 0.f};

  // prologue: stage step 0 into buf 0
  #pragma unroll
  for (int q = 0; q < 2; ++q) gload16(asrc[q], A0 + adst[q]);
  #pragma unroll
  for (int q = 0; q < 4; ++q) gload16(bsrc[q], B0 + bdst[q]);

  const int NSTEP = NSUBP / 128;   // 32
  for (int t = 0; t < NSTEP; ++t) {
    __syncthreads();
    int cur = t & 1;
    if (t + 1 < NSTEP) {
      int kn = (t + 1) * 128;
      char* nA = A0 + (cur ^ 1) * 8192;
      char* nB = B0 + (cur ^ 1) * 16384;
      #pragma unroll
      for (int q = 0; q < 2; ++q) {
        const float* sA = (kn + aok[q] < NSUB) ? (asrc[q] + kn) : asrc[q];
        gload16(sA, nA + adst[q]);                 // pad cols: garbage x B=0
      }
      #pragma unroll
      for (int q = 0; q < 4; ++q)
        gload16(bsrc[q] + kn, nB + bdst[q]);
    }
    const char* Ab = A0 + cur * 8192;
    const char* Bb = B0 + cur * 16384;
    #pragma unroll
    for (int kk = 0; kk < 4; ++kk) {
      f32x4 a0 = *(const f32x4*)(Ab + aoff[kk]);
      f32x4 a1 = *(const f32x4*)(Ab + (aoff[kk] ^ 16));
      bf16x8 afr;
      afr[0] = f2bf(a0.x); afr[1] = f2bf(a0.y); afr[2] = f2bf(a0.z); afr[3] = f2bf(a0.w);
      afr[4] = f2bf(a1.x); afr[5] = f2bf(a1.y); afr[6] = f2bf(a1.z); afr[7] = f2bf(a1.w);
      bf16x8 bfr = *(const bf16x8*)(Bb + boff[kk]);
      acc = __builtin_amdgcn_mfma_f32_16x16x32_bf16(afr, bfr, acc, 0, 0, 0);
    }
  }

  float* P = out + (size_t)s * NSUB * HID;
  float bv = (MODE == 1) ? bias[cl] : 0.f;
  #pragma unroll
  for (int r = 0; r < 4; ++r) {
    int row = m0 + g * 4 + r;
    float v = acc[r];
    if (MODE == 1) v = fmaxf(v + bv, 0.f);
    P[(size_t)row * HID + cl] = v;
  }
}

// ---------------- reduce layer-1 partial + bias + relu, fused h@W2 -> Pt2 (bf16 ^T, NSUBP)
__global__ __launch_bounds__(256) void k_reduce1(const float* __restrict__ part,
                                                 const float* __restrict__ b1,
                                                 const float* __restrict__ W2,
                                                 short* __restrict__ Pt2) {
  __shared__ float h[32][65];
  int bid = blockIdx.x;
  int s = bid / 125, i0 = (bid - s * 125) * 32;
  int t = threadIdx.x;
  int r = t >> 3, c8 = (t & 7) * 8;
  const float* P0 = part + ((size_t)s * NSUB + i0 + r) * HID + c8;
  #pragma unroll
  for (int u = 0; u < 8; ++u)
    h[r][c8 + u] = fmaxf(P0[u] + b1[c8 + u], 0.f);
  __syncthreads();
  int j = t & 63, ib = t >> 6;
  float acc[8];
  #pragma unroll
  for (int u = 0; u < 8; ++u) acc[u] = 0.f;
  for (int k = 0; k < HID; ++k) {
    float w = W2[k * HID + j];
    #pragma unroll
    for (int u = 0; u < 8; ++u) acc[u] += h[ib * 8 + u][k] * w;
  }
  bf16x8 o;
  #pragma unroll
  for (int u = 0; u < 8; ++u) o[u] = f2bf(acc[u]);
  *(bf16x8*)(Pt2 + ((size_t)s * HID + j) * NSUBP + i0 + ib * 8) = o;
}

// ---------------- per-node attention over snapshots -> compact Zb (bf16)
__global__ __launch_bounds__(256) void k_attn(const float* __restrict__ H,
                                              const int* __restrict__ posIdx,
                                              const float* __restrict__ Wq, const float* __restrict__ bq,
                                              const float* __restrict__ Wk, const float* __restrict__ bk,
                                              const float* __restrict__ Wv, const float* __restrict__ bv,
                                              const float* __restrict__ Wo, const float* __restrict__ bo,
                                              const float* __restrict__ te,
                                              short* __restrict__ Zb) {
  __shared__ __align__(16) float xk[4][S][HID];
  __shared__ __align__(16) float qs[4][S][HID];
  __shared__ __align__(16) float ks[4][S][HID];
  __shared__ __align__(16) float vs[4][S][HID];
  __shared__ __align__(16) float os[4][S][HID];
  int w = threadIdx.x >> 6;
  int lane = threadIdx.x & 63;
  int n = blockIdx.x * 4 + w;
  int pi[S];
  #pragma unroll
  for (int s = 0; s < S; ++s) {
    pi[s] = posIdx[n * S + s];
    xk[w][s][lane] = (pi[s] >= 0) ? H[((size_t)s * NSUB + pi[s]) * HID + lane] : 0.f;
  }
  __syncthreads();
  float aq[S], ak[S], av[S];
  #pragma unroll
  for (int s = 0; s < S; ++s) { aq[s] = bq[lane]; ak[s] = bk[lane]; av[s] = bv[lane]; }
  for (int k = 0; k < HID; ++k) {
    float wq = Wq[k*HID + lane], wk_ = Wk[k*HID + lane], wv = Wv[k*HID + lane];
    #pragma unroll
    for (int s = 0; s < S; ++s) {
      float xv = xk[w][s][k];
      aq[s] += xv * wq; ak[s] += xv * wk_; av[s] += xv * wv;
    }
  }
  const float qscale = 0.35355339059327373f;
  #pragma unroll
  for (int s = 0; s < S; ++s) {
    qs[w][s][lane] = aq[s] * qscale;
    ks[w][s][lane] = ak[s];
    vs[w][s][lane] = av[s];
  }
  __syncthreads();
  int h = lane >> 3, sq = lane & 7;
  f32x4 q0 = *(const f32x4*)&qs[w][sq][h * DH];
  f32x4 q1 = *(const f32x4*)&qs[w][sq][h * DH + 4];
  float sc[S];
  #pragma unroll
  for (int t = 0; t < S; ++t) {
    f32x4 k0v = *(const f32x4*)&ks[w][t][h * DH];
    f32x4 k1v = *(const f32x4*)&ks[w][t][h * DH + 4];
    float d = q0.x*k0v.x + q0.y*k0v.y + q0.z*k0v.z + q0.w*k0v.w
            + q1.x*k1v.x + q1.y*k1v.y + q1.z*k1v.z + q1.w*k1v.w;
    sc[t] = d + te[(t - sq + S - 1) * NH + h];
  }
  float m = sc[0];
  #pragma unroll
  for (int t = 1; t < S; ++t) m = fmaxf(m, sc[t]);
  float sum = 0.f;
  #pragma unroll
  for (int t = 0; t < S; ++t) { sc[t] = expf(sc[t] - m); sum += sc[t]; }
  float inv = 1.f / sum;
  f32x4 o0 = (f32x4){0.f,0.f,0.f,0.f}, o1 = (f32x4){0.f,0.f,0.f,0.f};
  #pragma unroll
  for (int t = 0; t < S; ++t) {
    f32x4 v0 = *(const f32x4*)&vs[w][t][h * DH];
    f32x4 v1 = *(const f32x4*)&vs[w][t][h * DH + 4];
    #pragma unroll
    for (int u = 0; u < 4; ++u) { o0[u] += sc[t] * v0[u]; o1[u] += sc[t] * v1[u]; }
  }
  #pragma unroll
  for (int u = 0; u < 4; ++u) { o0[u] *= inv; o1[u] *= inv; }
  *(f32x4*)&os[w][sq][h * DH]     = o0;
  *(f32x4*)&os[w][sq][h * DH + 4] = o1;
  __syncthreads();
  float ao[S];
  #pragma unroll
  for (int s = 0; s < S; ++s) ao[s] = bo[lane];
  for (int k = 0; k < HID; ++k) {
    float wo = Wo[k*HID + lane];
    #pragma unroll
    for (int s = 0; s < S; ++s) ao[s] += os[w][s][k] * wo;
  }
  #pragma unroll
  for (int s = 0; s < S; ++s)
    if (pi[s] >= 0) Zb[((size_t)s * NSUB + pi[s]) * HID + lane] = f2bf(ao[s]);
}

// ---------------- out[s] = Z[s] @ Z[s]^T, XCD swizzle, LDS-transposed dwordx4 NT stores
__global__ __launch_bounds__(256) void k_dec(const short* __restrict__ Zb,
                                             float* __restrict__ out) {
  __shared__ __align__(16) float tr[4][16][68];
  int bid = blockIdx.x;
  int s = bid & 7;
  int tt = bid >> 3;
  int by = tt / 63, bx = tt - by * 63;
  int wave = threadIdx.x >> 6, lane = threadIdx.x & 63;
  int l15 = lane & 15, g = lane >> 4;
  int m0 = by * 64 + wave * 16;
  int n0 = bx * 64;
  const short* ZS = Zb + (size_t)s * NSUB * HID;
  int mrow = m0 + l15;
  int mc = mrow < NSUB ? mrow : NSUB - 1;
  bf16x8 a0 = *(const bf16x8*)(ZS + (size_t)mc * HID + g * 8);
  bf16x8 a1 = *(const bf16x8*)(ZS + (size_t)mc * HID + 32 + g * 8);
  f32x4 acc[4];
  #pragma unroll
  for (int nf = 0; nf < 4; ++nf) acc[nf] = (f32x4){0.f, 0.f, 0.f, 0.f};
  #pragma unroll
  for (int nf = 0; nf < 4; ++nf) {
    int ncol = n0 + nf * 16 + l15;
    int nc = ncol < NSUB ? ncol : NSUB - 1;
    bf16x8 b0 = *(const bf16x8*)(ZS + (size_t)nc * HID + g * 8);
    bf16x8 b1 = *(const bf16x8*)(ZS + (size_t)nc * HID + 32 + g * 8);
    acc[nf] = __builtin_amdgcn_mfma_f32_16x16x32_bf16(a0, b0, acc[nf], 0, 0, 0);
    acc[nf] = __builtin_amdgcn_mfma_f32_16x16x32_bf16(a1, b1, acc[nf], 0, 0, 0);
  }
  #pragma unroll
  for (int nf = 0; nf < 4; ++nf)
    #pragma unroll
    for (int r = 0; r < 4; ++r)
      tr[wave][g * 4 + r][nf * 16 + l15] = acc[nf][r];
  __syncthreads();
  float* outS = out + (size_t)s * NSUB * NSUB;
  #pragma unroll
  for (int p = 0; p < 4; ++p) {
    int rr = p * 4 + g;
    int grow = m0 + rr;
    int gcol = n0 + l15 * 4;
    f32x4 v = *(const f32x4*)&tr[wave][rr][l15 * 4];
    if (grow < NSUB && gcol < NSUB)
      __builtin_nontemporal_store(v, (f32x4*)(outS + (size_t)grow * NSUB + gcol));
  }
}

extern "C" void kernel_launch(void* const* d_in, const int* in_sizes, int n_in,
                              void* d_out, int out_size, void* d_ws, size_t ws_size,
                              hipStream_t stream) {
  const int*   nodes = (const int*)d_in[0];
  const float* adj   = (const float*)d_in[1];
  const float* emb   = (const float*)d_in[2];
  const float* W1    = (const float*)d_in[3];
  const float* b1    = (const float*)d_in[4];
  const float* W2    = (const float*)d_in[5];
  const float* b2    = (const float*)d_in[6];
  const float* te    = (const float*)d_in[7];
  const float* Wq    = (const float*)d_in[8];
  const float* bq    = (const float*)d_in[9];
  const float* Wk    = (const float*)d_in[10];
  const float* bk    = (const float*)d_in[11];
  const float* Wv    = (const float*)d_in[12];
  const float* bv    = (const float*)d_in[13];
  const float* Wo    = (const float*)d_in[14];
  const float* bo    = (const float*)d_in[15];
  float* outp = (float*)d_out;

  // ws: part 8MB | H 8MB | Pt (8*64*4096*2B = 4MB) | Zb 4MB | posIdx 0.64MB
  float* part = (float*)d_ws;
  float* H    = part + (size_t)S * NSUB * HID;
  short* Pt   = (short*)(H + (size_t)S * NSUB * HID);
  short* Zb   = Pt + (size_t)S * HID * NSUBP;
  int* posIdx = (int*)(Zb + (size_t)S * NSUB * HID);

  k_pos_init<<<(NTOT*S + 255)/256, 256, 0, stream>>>(posIdx);
  k_pos_scatter<<<(S*NSUB + 255)/256, 256, 0, stream>>>(nodes, posIdx);
  k_pt_pad<<<24, 256, 0, stream>>>(Pt);

  // GCN layer 1 (raw partial -> part; reduce fuses bias+relu+W2 -> Pt2)
  k_feat_w1<<<2000, 256, 0, stream>>>(nodes, emb, W1, Pt);
  k_adj<0><<<2000, 256, 0, stream>>>(adj, Pt, b1, part);
  k_reduce1<<<1000, 256, 0, stream>>>(part, b1, W2, Pt);
  // GCN layer 2 (epilogue fuses bias+relu -> H directly)
  k_adj<1><<<2000, 256, 0, stream>>>(adj, Pt, b2, H);
  // attention -> compact Z (bf16)
  k_attn<<<NTOT/4, 256, 0, stream>>>(H, posIdx, Wq, bq, Wk, bk, Wv, bv, Wo, bo, te, Zb);
  // decoder
  k_dec<<<63*63*8, 256, 0, stream>>>(Zb, outp);
}

// Round 12
// 471.218 us; speedup vs baseline: 1.1883x; 1.1883x over previous
//
#include <hip/hip_runtime.h>
#include <hip/hip_bf16.h>
#include <cstdint>

#define S 8
#define NTOT 20000
#define NSUB 4000
#define NSUBP 4032   // padded K for Pt (63 x 64); pad cols are zero
#define NST 63       // K-steps of BK=64
#define F 128
#define HID 64
#define NH 8
#define DH 8

typedef __attribute__((ext_vector_type(8))) short bf16x8;
typedef __attribute__((ext_vector_type(4))) short bf16x4;
typedef __attribute__((ext_vector_type(4))) float f32x4;

__device__ __forceinline__ short f2bf(float f) {
  union { __hip_bfloat16 h; short s; } u;
  u.h = __float2bfloat16(f);
  return u.s;
}

__device__ __forceinline__ void gload16(const void* gsrc, void* ldst) {
  __builtin_amdgcn_global_load_lds(
      (const __attribute__((address_space(1))) void*)gsrc,
      (__attribute__((address_space(3))) void*)ldst, 16, 0, 0);
}

// ---------------- position map
__global__ void k_pos_init(int* __restrict__ posIdx) {
  int t = blockIdx.x * 256 + threadIdx.x;
  if (t < NTOT * S) posIdx[t] = -1;
}

__global__ void k_pos_scatter(const int* __restrict__ nodes, int* __restrict__ posIdx) {
  int t = blockIdx.x * 256 + threadIdx.x;
  if (t < S * NSUB) {
    int s = t / NSUB, i = t - s * NSUB;
    posIdx[nodes[t] * S + s] = i;
  }
}

// ---------------- zero the K-pad columns of a Pt buffer (cols 4000..4031)
__global__ void k_pt_pad(short* __restrict__ Pt) {
  int t = blockIdx.x * 256 + threadIdx.x;      // 0..2047
  int seg = t >> 2, off = (t & 3) * 8;         // seg = s*64 + j
  bf16x8 z = (bf16x8){0,0,0,0,0,0,0,0};
  *(bf16x8*)(Pt + (size_t)seg * NSUBP + NSUB + off) = z;
}

// ---------------- W2t bf16: W2t[j*64+k] = bf16(W2[k*64+j])
__global__ void k_w2t(const float* __restrict__ W2, short* __restrict__ W2t) {
  int t = blockIdx.x * 256 + threadIdx.x;      // 0..4095
  int j = t >> 6, k = t & 63;
  W2t[t] = f2bf(W2[k * HID + j]);
}

// ---------------- Pt1 = (emb[nodes] @ W1)^T bf16 (stride NSUBP)
__global__ __launch_bounds__(256) void k_feat_w1(const int* __restrict__ nodes,
                                                 const float* __restrict__ emb,
                                                 const float* __restrict__ W1,
                                                 short* __restrict__ Pt) {
  __shared__ __align__(16) float feat[16][F];
  __shared__ float tr[64][17];
  int t = threadIdx.x;
  int s = blockIdx.x / 250;
  int i0 = (blockIdx.x - s * 250) * 16;
  int gr0 = blockIdx.x * 16;
  int lr = t >> 4, lc = (t & 15) * 8;
  int n = nodes[gr0 + lr];
  *(f32x4*)&feat[lr][lc]     = *(const f32x4*)(emb + (size_t)n * F + lc);
  *(f32x4*)&feat[lr][lc + 4] = *(const f32x4*)(emb + (size_t)n * F + lc + 4);
  __syncthreads();
  int j = t & 63, ig = t >> 6;
  float acc[4] = {0.f, 0.f, 0.f, 0.f};
  for (int k = 0; k < F; ++k) {
    float w = W1[k * HID + j];
    #pragma unroll
    for (int i = 0; i < 4; ++i) acc[i] += feat[ig * 4 + i][k] * w;
  }
  #pragma unroll
  for (int i = 0; i < 4; ++i) tr[j][ig * 4 + i] = acc[i];
  __syncthreads();
  int jr = t >> 2, seg = (t & 3) * 4;
  bf16x4 o;
  #pragma unroll
  for (int u = 0; u < 4; ++u) o[u] = f2bf(tr[jr][seg + u]);
  *(bf16x4*)(Pt + ((size_t)s * HID + jr) * NSUBP + i0 + seg) = o;
}

// ---------------- adj GEMM: BK=64, LDS-staged, dbuf (round-10 structure)
// grid 504: s=bid&7 (XCD), mb=bid>>3. block 256 = 4 waves, BM=64.
// MODE 0: fused epilogue relu(acc+b1) @ W2t -> Pt2 bf16 (transposed layout).
// MODE 1: relu(acc+bias) -> H fp32.
template<int MODE>
__global__ __launch_bounds__(256) void k_adj(const float* __restrict__ adj,
                                             const short* __restrict__ Pt,
                                             const float* __restrict__ bias,
                                             const short* __restrict__ W2t,
                                             float* __restrict__ outF,
                                             short* __restrict__ outB) {
  __shared__ __align__(16) float As[2][64 * 64];   // row*256B, chunk^(row&7) swizzle
  __shared__ __align__(16) short Bs[2][64 * 64];   // col*128B, chunk^(col&7) swizzle
  __shared__ __align__(16) short hb[MODE == 0 ? 4 * 16 * 64 : 4];  // h tile, bf16 swz
  __shared__ __align__(16) short tb[MODE == 0 ? 4 * 64 * 24 : 4];  // transposed P2
  int bid = blockIdx.x;
  int s = bid & 7;
  int mb = bid >> 3;
  int tid = threadIdx.x;
  int w = tid >> 6, lane = tid & 63, l15 = lane & 15, g = lane >> 4;
  int m0 = mb * 64;
  const float* adjS = adj + (size_t)s * NSUB * NSUB;
  const short* PtS  = Pt  + (size_t)s * HID * NSUBP;

  // ---- A staging map: 4 rounds; round p: row p*16 + w*4 + (lane>>4)
  int rbase = w * 4 + (lane >> 4);
  int sigA = l15;
  int clogA = (sigA & 8) | ((sigA & 7) ^ (rbase & 7));
  int acolf = clogA * 4;
  const float* arow[4];
  #pragma unroll
  for (int p = 0; p < 4; ++p) {
    int rg = m0 + p * 16 + rbase;
    rg = rg < NSUB ? rg : NSUB - 1;
    arow[p] = adjS + (size_t)rg * NSUB;
  }
  // ---- B staging map: 2 rounds; round p: col p*32 + w*8 + (lane>>3)
  int sigB = lane & 7;
  int clogB = sigB ^ ((lane >> 3) & 7);
  const short* bsrc[2];
  #pragma unroll
  for (int p = 0; p < 2; ++p) {
    int col = p * 32 + w * 8 + (lane >> 3);
    bsrc[p] = PtS + (size_t)col * NSUBP + clogB * 8;
  }

  char* As0 = (char*)&As[0][0];
  char* Bs0 = (char*)&Bs[0][0];
  int wb = w * 1024;

  // ---- fragment-read byte offsets
  int arowf = w * 16 + l15;
  int aoff = arowf * 256 + (((2 * g) ^ (arowf & 7)) * 16);
  int boff[4];
  #pragma unroll
  for (int nf = 0; nf < 4; ++nf) {
    int col = nf * 16 + l15;
    boff[nf] = col * 128 + ((g ^ (col & 7)) * 16);
  }

  f32x4 acc[4];
  #pragma unroll
  for (int nf = 0; nf < 4; ++nf) acc[nf] = (f32x4){0.f, 0.f, 0.f, 0.f};

  // ---- prologue: stage step 0 into buf 0
  #pragma unroll
  for (int p = 0; p < 4; ++p)
    gload16(arow[p] + acolf, As0 + p * 4096 + wb);
  #pragma unroll
  for (int p = 0; p < 2; ++p)
    gload16(bsrc[p], Bs0 + p * 4096 + wb);

  for (int t = 0; t < NST; ++t) {
    __syncthreads();
    int cur = t & 1;
    if (t + 1 < NST) {
      int kn = (t + 1) * 64;
      bool ok = (kn + acolf) < NSUB;
      char* nA = As0 + (cur ^ 1) * 16384;
      char* nB = Bs0 + (cur ^ 1) * 8192;
      #pragma unroll
      for (int p = 0; p < 4; ++p)
        gload16(ok ? (arow[p] + kn + acolf) : arow[p], nA + p * 4096 + wb);
      #pragma unroll
      for (int p = 0; p < 2; ++p)
        gload16(bsrc[p] + kn, nB + p * 4096 + wb);
    }
    const char* Ab = As0 + cur * 16384;
    const char* Bb = Bs0 + cur * 8192;
    f32x4 a0 = *(const f32x4*)(Ab + aoff);
    f32x4 a1 = *(const f32x4*)(Ab + (aoff ^ 16));
    f32x4 a2 = *(const f32x4*)(Ab + 128 + aoff);
    f32x4 a3 = *(const f32x4*)(Ab + 128 + (aoff ^ 16));
    bf16x8 af0, af1;
    af0[0] = f2bf(a0.x); af0[1] = f2bf(a0.y); af0[2] = f2bf(a0.z); af0[3] = f2bf(a0.w);
    af0[4] = f2bf(a1.x); af0[5] = f2bf(a1.y); af0[6] = f2bf(a1.z); af0[7] = f2bf(a1.w);
    af1[0] = f2bf(a2.x); af1[1] = f2bf(a2.y); af1[2] = f2bf(a2.z); af1[3] = f2bf(a2.w);
    af1[4] = f2bf(a3.x); af1[5] = f2bf(a3.y); af1[6] = f2bf(a3.z); af1[7] = f2bf(a3.w);
    #pragma unroll
    for (int nf = 0; nf < 4; ++nf) {
      bf16x8 b0 = *(const bf16x8*)(Bb + boff[nf]);
      bf16x8 b1 = *(const bf16x8*)(Bb + (boff[nf] ^ 64));
      acc[nf] = __builtin_amdgcn_mfma_f32_16x16x32_bf16(af0, b0, acc[nf], 0, 0, 0);
      acc[nf] = __builtin_amdgcn_mfma_f32_16x16x32_bf16(af1, b1, acc[nf], 0, 0, 0);
    }
  }

  if constexpr (MODE == 1) {
    float* P = outF + (size_t)s * NSUB * HID;
    #pragma unroll
    for (int nf = 0; nf < 4; ++nf) {
      int col = nf * 16 + l15;
      float bv = bias[col];
      #pragma unroll
      for (int r = 0; r < 4; ++r) {
        int row = m0 + w * 16 + g * 4 + r;
        if (row < NSUB) P[(size_t)row * HID + col] = fmaxf(acc[nf][r] + bv, 0.f);
      }
    }
  } else {
    // ---- fused: h = relu(acc + b1[col]); Pt2 = bf16(h @ W2) transposed
    // E1: h -> hb[w] as bf16 rows [r16][k=col], chunk ^ (r16&7)
    char* hbw = (char*)&hb[0] + w * 2048;
    #pragma unroll
    for (int nf = 0; nf < 4; ++nf) {
      int col = nf * 16 + l15;
      float bv = bias[col];
      #pragma unroll
      for (int r = 0; r < 4; ++r) {
        int r16 = g * 4 + r;
        float hv = fmaxf(acc[nf][r] + bv, 0.f);
        int byte = r16 * 128 + (((col >> 3) ^ (r16 & 7)) * 16) + (col & 7) * 2;
        *(short*)(hbw + byte) = f2bf(hv);
      }
    }
    __syncthreads();
    // E2: 8 MFMA vs W2t; write D-frags transposed into tb[w][j][i16]
    short* tbw = &tb[0] + w * 1536;
    #pragma unroll
    for (int jf = 0; jf < 4; ++jf) {
      f32x4 o = (f32x4){0.f, 0.f, 0.f, 0.f};
      #pragma unroll
      for (int kk = 0; kk < 2; ++kk) {
        bf16x8 a = *(const bf16x8*)(hbw + l15 * 128 + (((kk * 4 + g) ^ (l15 & 7)) * 16));
        bf16x8 b = *(const bf16x8*)(W2t + (jf * 16 + l15) * HID + kk * 32 + g * 8);
        o = __builtin_amdgcn_mfma_f32_16x16x32_bf16(a, b, o, 0, 0, 0);
      }
      #pragma unroll
      for (int r = 0; r < 4; ++r)
        tbw[(jf * 16 + l15) * 24 + g * 4 + r] = f2bf(o[r]);
    }
    __syncthreads();
    // E3: coalesced bf16x8 stores (zeros for pad rows >= NSUB)
    int j = tid >> 2, wv = tid & 3;
    #pragma unroll
    for (int c = 0; c < 2; ++c) {
      int gi = m0 + wv * 16 + c * 8;
      bf16x8 v = *(const bf16x8*)(&tb[0] + wv * 1536 + j * 24 + c * 8);
      if (gi >= NSUB) v = (bf16x8){0,0,0,0,0,0,0,0};
      *(bf16x8*)(outB + ((size_t)s * HID + j) * NSUBP + gi) = v;
    }
  }
}

// ---------------- per-node attention over snapshots -> compact Zb (bf16)
__global__ __launch_bounds__(256) void k_attn(const float* __restrict__ H,
                                              const int* __restrict__ posIdx,
                                              const float* __restrict__ Wq, const float* __restrict__ bq,
                                              const float* __restrict__ Wk, const float* __restrict__ bk,
                                              const float* __restrict__ Wv, const float* __restrict__ bv,
                                              const float* __restrict__ Wo, const float* __restrict__ bo,
                                              const float* __restrict__ te,
                                              short* __restrict__ Zb) {
  __shared__ __align__(16) float xk[4][S][HID];
  __shared__ __align__(16) float qs[4][S][HID];
  __shared__ __align__(16) float ks[4][S][HID];
  __shared__ __align__(16) float vs[4][S][HID];
  __shared__ __align__(16) float os[4][S][HID];
  int w = threadIdx.x >> 6;
  int lane = threadIdx.x & 63;
  int n = blockIdx.x * 4 + w;
  int pi[S];
  #pragma unroll
  for (int s = 0; s < S; ++s) {
    pi[s] = posIdx[n * S + s];
    xk[w][s][lane] = (pi[s] >= 0) ? H[((size_t)s * NSUB + pi[s]) * HID + lane] : 0.f;
  }
  __syncthreads();
  float aq[S], ak[S], av[S];
  #pragma unroll
  for (int s = 0; s < S; ++s) { aq[s] = bq[lane]; ak[s] = bk[lane]; av[s] = bv[lane]; }
  for (int k = 0; k < HID; ++k) {
    float wq = Wq[k*HID + lane], wk_ = Wk[k*HID + lane], wv = Wv[k*HID + lane];
    #pragma unroll
    for (int s = 0; s < S; ++s) {
      float xv = xk[w][s][k];
      aq[s] += xv * wq; ak[s] += xv * wk_; av[s] += xv * wv;
    }
  }
  const float qscale = 0.35355339059327373f;
  #pragma unroll
  for (int s = 0; s < S; ++s) {
    qs[w][s][lane] = aq[s] * qscale;
    ks[w][s][lane] = ak[s];
    vs[w][s][lane] = av[s];
  }
  __syncthreads();
  int h = lane >> 3, sq = lane & 7;
  f32x4 q0 = *(const f32x4*)&qs[w][sq][h * DH];
  f32x4 q1 = *(const f32x4*)&qs[w][sq][h * DH + 4];
  float sc[S];
  #pragma unroll
  for (int t = 0; t < S; ++t) {
    f32x4 k0v = *(const f32x4*)&ks[w][t][h * DH];
    f32x4 k1v = *(const f32x4*)&ks[w][t][h * DH + 4];
    float d = q0.x*k0v.x + q0.y*k0v.y + q0.z*k0v.z + q0.w*k0v.w
            + q1.x*k1v.x + q1.y*k1v.y + q1.z*k1v.z + q1.w*k1v.w;
    sc[t] = d + te[(t - sq + S - 1) * NH + h];
  }
  float m = sc[0];
  #pragma unroll
  for (int t = 1; t < S; ++t) m = fmaxf(m, sc[t]);
  float sum = 0.f;
  #pragma unroll
  for (int t = 0; t < S; ++t) { sc[t] = expf(sc[t] - m); sum += sc[t]; }
  float inv = 1.f / sum;
  f32x4 o0 = (f32x4){0.f,0.f,0.f,0.f}, o1 = (f32x4){0.f,0.f,0.f,0.f};
  #pragma unroll
  for (int t = 0; t < S; ++t) {
    f32x4 v0 = *(const f32x4*)&vs[w][t][h * DH];
    f32x4 v1 = *(const f32x4*)&vs[w][t][h * DH + 4];
    #pragma unroll
    for (int u = 0; u < 4; ++u) { o0[u] += sc[t] * v0[u]; o1[u] += sc[t] * v1[u]; }
  }
  #pragma unroll
  for (int u = 0; u < 4; ++u) { o0[u] *= inv; o1[u] *= inv; }
  *(f32x4*)&os[w][sq][h * DH]     = o0;
  *(f32x4*)&os[w][sq][h * DH + 4] = o1;
  __syncthreads();
  float ao[S];
  #pragma unroll
  for (int s = 0; s < S; ++s) ao[s] = bo[lane];
  for (int k = 0; k < HID; ++k) {
    float wo = Wo[k*HID + lane];
    #pragma unroll
    for (int s = 0; s < S; ++s) ao[s] += os[w][s][k] * wo;
  }
  #pragma unroll
  for (int s = 0; s < S; ++s)
    if (pi[s] >= 0) Zb[((size_t)s * NSUB + pi[s]) * HID + lane] = f2bf(ao[s]);
}

// ---------------- out[s] = Z[s] @ Z[s]^T, XCD swizzle, LDS-transposed dwordx4 NT stores
__global__ __launch_bounds__(256) void k_dec(const short* __restrict__ Zb,
                                             float* __restrict__ out) {
  __shared__ __align__(16) float tr[4][16][68];
  int bid = blockIdx.x;
  int s = bid & 7;
  int tt = bid >> 3;
  int by = tt / 63, bx = tt - by * 63;
  int wave = threadIdx.x >> 6, lane = threadIdx.x & 63;
  int l15 = lane & 15, g = lane >> 4;
  int m0 = by * 64 + wave * 16;
  int n0 = bx * 64;
  const short* ZS = Zb + (size_t)s * NSUB * HID;
  int mrow = m0 + l15;
  int mc = mrow < NSUB ? mrow : NSUB - 1;
  bf16x8 a0 = *(const bf16x8*)(ZS + (size_t)mc * HID + g * 8);
  bf16x8 a1 = *(const bf16x8*)(ZS + (size_t)mc * HID + 32 + g * 8);
  f32x4 acc[4];
  #pragma unroll
  for (int nf = 0; nf < 4; ++nf) acc[nf] = (f32x4){0.f, 0.f, 0.f, 0.f};
  #pragma unroll
  for (int nf = 0; nf < 4; ++nf) {
    int ncol = n0 + nf * 16 + l15;
    int nc = ncol < NSUB ? ncol : NSUB - 1;
    bf16x8 b0 = *(const bf16x8*)(ZS + (size_t)nc * HID + g * 8);
    bf16x8 b1 = *(const bf16x8*)(ZS + (size_t)nc * HID + 32 + g * 8);
    acc[nf] = __builtin_amdgcn_mfma_f32_16x16x32_bf16(a0, b0, acc[nf], 0, 0, 0);
    acc[nf] = __builtin_amdgcn_mfma_f32_16x16x32_bf16(a1, b1, acc[nf], 0, 0, 0);
  }
  #pragma unroll
  for (int nf = 0; nf < 4; ++nf)
    #pragma unroll
    for (int r = 0; r < 4; ++r)
      tr[wave][g * 4 + r][nf * 16 + l15] = acc[nf][r];
  __syncthreads();
  float* outS = out + (size_t)s * NSUB * NSUB;
  #pragma unroll
  for (int p = 0; p < 4; ++p) {
    int rr = p * 4 + g;
    int grow = m0 + rr;
    int gcol = n0 + l15 * 4;
    f32x4 v = *(const f32x4*)&tr[wave][rr][l15 * 4];
    if (grow < NSUB && gcol < NSUB)
      __builtin_nontemporal_store(v, (f32x4*)(outS + (size_t)grow * NSUB + gcol));
  }
}

extern "C" void kernel_launch(void* const* d_in, const int* in_sizes, int n_in,
                              void* d_out, int out_size, void* d_ws, size_t ws_size,
                              hipStream_t stream) {
  const int*   nodes = (const int*)d_in[0];
  const float* adj   = (const float*)d_in[1];
  const float* emb   = (const float*)d_in[2];
  const float* W1    = (const float*)d_in[3];
  const float* b1    = (const float*)d_in[4];
  const float* W2    = (const float*)d_in[5];
  const float* b2    = (const float*)d_in[6];
  const float* te    = (const float*)d_in[7];
  const float* Wq    = (const float*)d_in[8];
  const float* bq    = (const float*)d_in[9];
  const float* Wk    = (const float*)d_in[10];
  const float* bk    = (const float*)d_in[11];
  const float* Wv    = (const float*)d_in[12];
  const float* bv    = (const float*)d_in[13];
  const float* Wo    = (const float*)d_in[14];
  const float* bo    = (const float*)d_in[15];
  float* outp = (float*)d_out;

  // ws: H 8MB | Pt1 ~4MB | Pt2 ~4MB | Zb 4MB | posIdx 0.64MB | W2t 8KB
  float* H    = (float*)d_ws;
  short* Pt1  = (short*)(H + (size_t)S * NSUB * HID);
  short* Pt2  = Pt1 + (size_t)S * HID * NSUBP;
  short* Zb   = Pt2 + (size_t)S * HID * NSUBP;
  int* posIdx = (int*)(Zb + (size_t)S * NSUB * HID);
  short* W2t  = (short*)(posIdx + (size_t)NTOT * S);

  k_pos_init<<<(NTOT*S + 255)/256, 256, 0, stream>>>(posIdx);
  k_pos_scatter<<<(S*NSUB + 255)/256, 256, 0, stream>>>(nodes, posIdx);
  k_pt_pad<<<8, 256, 0, stream>>>(Pt1);
  k_w2t<<<16, 256, 0, stream>>>(W2, W2t);

  // GCN layer 1 (fused bias+relu+W2 epilogue -> Pt2)
  k_feat_w1<<<2000, 256, 0, stream>>>(nodes, emb, W1, Pt1);
  k_adj<0><<<504, 256, 0, stream>>>(adj, Pt1, b1, W2t, nullptr, Pt2);
  // GCN layer 2 (epilogue fuses bias+relu -> H)
  k_adj<1><<<504, 256, 0, stream>>>(adj, Pt2, b2, nullptr, H, nullptr);
  // attention -> compact Z (bf16)
  k_attn<<<NTOT/4, 256, 0, stream>>>(H, posIdx, Wq, bq, Wk, bk, Wv, bv, Wo, bo, te, Zb);
  // decoder
  k_dec<<<63*63*8, 256, 0, stream>>>(Zb, outp);
}